// Round 13
// baseline (658.507 us; speedup 1.0000x reference)
//
#include <hip/hip_runtime.h>
#include <hip/hip_bf16.h>
#include <cmath>

#define HW_ 16384
#define IMG_W 128
#define IMG_H 128
#define DIM_ 256
#define D3_ 768
#define HEADS_ 4
#define C_ 64
#define B_ 8

typedef unsigned short ushort_t;
typedef __attribute__((ext_vector_type(8))) short short8v;
typedef __attribute__((ext_vector_type(16))) float f32x16;

#define GLL16(gp, lp) __builtin_amdgcn_global_load_lds( \
    (const __attribute__((address_space(1))) void*)(gp), \
    (__attribute__((address_space(3))) void*)(lp), 16, 0, 0)

static __device__ __forceinline__ ushort_t f2bf_bits(float v) {
  __hip_bfloat16 h = __float2bfloat16(v);   // RNE — must match k0_wsplit
  return *reinterpret_cast<ushort_t*>(&h);
}
static __device__ __forceinline__ float bf2f(ushort_t u) {
  return __uint_as_float(((unsigned int)u) << 16);
}

// ---------------------------------------------------------------------------
// K0a: split W (w_qkv rows 0..767, gw1 rows 768..895) into bf16 hi/lo (RNE).
// ---------------------------------------------------------------------------
__global__ __launch_bounds__(256) void k0_wsplit(
    const float* __restrict__ wqkv, const float* __restrict__ gw1,
    ushort_t* __restrict__ WH, ushort_t* __restrict__ WL)
{
  const int row = blockIdx.x;
  const int t = threadIdx.x;
  const float* src = (row < 768) ? (wqkv + (size_t)row * DIM_)
                                 : (gw1 + (size_t)(row - 768) * DIM_);
  const float v = src[t];
  const ushort_t hb = f2bf_bits(v);
  WH[(size_t)row * DIM_ + t] = hb;
  WL[(size_t)row * DIM_ + t] = f2bf_bits(v - bf2f(hb));
}

// ---------------------------------------------------------------------------
// K1 body (R10/R12 verbatim): MFMA GEMM, bf16 hi/lo, 3 MFMA/product,
// 2-phase BK=32, 64KB LDS, 1x4 wave grid, consumer RNE split of B.
// ---------------------------------------------------------------------------
__device__ __forceinline__ void k1_body(
    unsigned char* lds, int t, int cb, int rb, int s,
    const ushort_t* __restrict__ WH, const ushort_t* __restrict__ WL,
    const float* __restrict__ x, const float* __restrict__ gb1,
    const float* __restrict__ gw2, const float* __restrict__ gb2,
    float* __restrict__ qkvraw, float* __restrict__ gpart, int bbase)
{
  const int row0 = rb * 128, col0 = cb * 128;
  const float* xb = x + (size_t)(bbase + s) * DIM_ * HW_;

  ushort_t* ldsA = (ushort_t*)lds;                  // [2][8192] shorts
  float*    ldsB = (float*)(lds + 32768);           // [2][4096] floats

  const int lane = t & 63, wid = t >> 6;
  const int rr = lane & 31, lh = lane >> 5;

  const size_t arowb = (size_t)(row0 + wid * 32 + rr) * DIM_;

  f32x16 acc[4];
#pragma unroll
  for (int mi = 0; mi < 4; ++mi)
#pragma unroll
    for (int r = 0; r < 16; ++r) acc[mi][r] = 0.f;

  auto STAGE = [&](int pb, int kt) {
    ushort_t* abase = ldsA + pb * 8192;
#pragma unroll
    for (int i = 0; i < 2; ++i) {
      const int koff = kt * 32 + i * 16 + lh * 8;
      ushort_t* dst = abase + (wid * 2 + i) * 512;  // wave-uniform
      GLL16(WH + arowb + koff, dst);
      GLL16(WL + arowb + koff, dst + 4096);
    }
    float* bbase2 = ldsB + pb * 4096;
#pragma unroll
    for (int j = 0; j < 4; ++j) {
      const int crow = wid * 8 + j * 2 + lh;        // c within 32
      const float* src = xb + (size_t)(kt * 32 + crow) * HW_ + col0 + rr * 4;
      GLL16(src, bbase2 + (wid * 8 + j * 2) * 128); // wave-uniform
    }
  };

  auto COMPUTE = [&](int pb) {
    const ushort_t* pAH = ldsA + pb * 8192;
    const ushort_t* pAL = pAH + 4096;
    const float* bx = ldsB + pb * 4096;
    const int lo = lane * 8;
    const int pidx = wid * 32 + rr;                 // this wave's p column
#pragma unroll
    for (int ks = 0; ks < 2; ++ks) {
      short8v ah[4], al[4];
#pragma unroll
      for (int mi = 0; mi < 4; ++mi) {
        const int base = mi * 1024 + ks * 512 + lo;
        ah[mi] = *(const short8v*)(pAH + base);
        al[mi] = *(const short8v*)(pAL + base);
      }
      short8v bh, bl;
#pragma unroll
      for (int j = 0; j < 8; ++j) {
        const float fv = bx[(ks * 16 + lh * 8 + j) * 128 + pidx];
        const ushort_t hb = f2bf_bits(fv);            // RNE hi
        bh[j] = (short)hb;
        bl[j] = (short)f2bf_bits(fv - bf2f(hb));      // RNE lo
      }
#pragma unroll
      for (int mi = 0; mi < 4; ++mi) {
        acc[mi] = __builtin_amdgcn_mfma_f32_32x32x16_bf16(ah[mi], bh, acc[mi], 0, 0, 0);
        acc[mi] = __builtin_amdgcn_mfma_f32_32x32x16_bf16(ah[mi], bl, acc[mi], 0, 0, 0);
        acc[mi] = __builtin_amdgcn_mfma_f32_32x32x16_bf16(al[mi], bh, acc[mi], 0, 0, 0);
      }
    }
  };

  STAGE(0, 0);
  __syncthreads();

  for (int kt = 0; kt < 8; ++kt) {
    const int pb = kt & 1;
    if (kt < 7) STAGE(pb ^ 1, kt + 1);
    COMPUTE(pb);
    __syncthreads();
  }

  // Epilogue. C/D layout: col=lane&31, row=(reg&3)+8*(reg>>2)+4*(lane>>5)
  const int cl = lane & 31;
  if (rb < 6) {
    const int p = col0 + wid * 32 + cl;
#pragma unroll
    for (int mi = 0; mi < 4; ++mi)
#pragma unroll
      for (int r = 0; r < 16; ++r) {
        const int row = (r & 3) + 8 * (r >> 2) + 4 * lh;
        const int m = row0 + mi * 32 + row;
        qkvraw[((size_t)s * D3_ + m) * HW_ + p] = acc[mi][r];
      }
  } else {
    // fused gate: per-pixel sv = sum_c relu(acc+gb1[c]) * gw2[c]
    float ps = 0.f;
#pragma unroll
    for (int mi = 0; mi < 4; ++mi)
#pragma unroll
      for (int r = 0; r < 16; ++r) {
        const int row = (r & 3) + 8 * (r >> 2) + 4 * lh;
        const int gr = mi * 32 + row;
        ps += fmaxf(acc[mi][r] + gb1[gr], 0.f) * gw2[gr];
      }
    ps += __shfl_xor(ps, 32, 64);
    float* sred = (float*)lds;   // safe: final loop barrier drained all reads
    float* red2 = sred + 128;
    if (lh == 0) sred[wid * 32 + cl] = ps;
    __syncthreads();
    float sig = 0.f;
    if (t < 128) {
      const float sv = sred[t] + gb2[0];
      sig = 1.f / (1.f + expf(-sv));
    }
    __syncthreads();
    red2[t] = sig;
    __syncthreads();
    for (int o = 128; o > 0; o >>= 1) {
      if (t < o) red2[t] += red2[t + o];
      __syncthreads();
    }
    if (t == 0) gpart[(size_t)(bbase + s) * 128 + cb] = red2[0];
  }
}

// ---------------------------------------------------------------------------
// K3b body (R12 verbatim): Gram partials over 512-pixel chunks, fp32 input.
// qs/ks are [64][68] float tiles supplied by the caller.
// ---------------------------------------------------------------------------
__device__ __forceinline__ void k3b_body(
    float (*qs)[68], float (*ks)[68], int t, int chunk, int h, int s, int b,
    const float* __restrict__ uni, float* __restrict__ S_part)
{
  const int p0 = chunk * 512;
  const float* qdw = uni + (size_t)s * 512 * HW_;
  const float* kdw = qdw + (size_t)DIM_ * HW_;

  const int rc = t >> 4, dc = t & 15;

  float acc[4][4];
#pragma unroll
  for (int i = 0; i < 4; ++i)
#pragma unroll
    for (int j = 0; j < 4; ++j) acc[i][j] = 0.f;

  const float* qbase = qdw + (size_t)h * 64 * HW_ + p0;
  const float* kbase = kdw + (size_t)h * 64 * HW_ + p0;

  for (int kk = 0; kk < 512; kk += 64) {
    __syncthreads();
#pragma unroll
    for (int j = 0; j < 4; ++j) {
      const int lin = t + j * 256;
      const int c = lin >> 4;
      const int px0 = (lin & 15) << 2;
      const float4 qv = *(const float4*)(qbase + (size_t)c * HW_ + kk + px0);
      const float4 kv = *(const float4*)(kbase + (size_t)c * HW_ + kk + px0);
      qs[px0 + 0][c] = qv.x; qs[px0 + 1][c] = qv.y;
      qs[px0 + 2][c] = qv.z; qs[px0 + 3][c] = qv.w;
      ks[px0 + 0][c] = kv.x; ks[px0 + 1][c] = kv.y;
      ks[px0 + 2][c] = kv.z; ks[px0 + 3][c] = kv.w;
    }
    __syncthreads();
#pragma unroll 4
    for (int p = 0; p < 64; ++p) {
      const float4 q4 = *(const float4*)&qs[p][rc * 4];
      const float4 k4 = *(const float4*)&ks[p][dc * 4];
      const float qa[4] = {q4.x, q4.y, q4.z, q4.w};
      const float ka[4] = {k4.x, k4.y, k4.z, k4.w};
#pragma unroll
      for (int i = 0; i < 4; ++i)
#pragma unroll
        for (int jj = 0; jj < 4; ++jj) acc[i][jj] += qa[i] * ka[jj];
    }
  }
  float* op = S_part + (((size_t)(b * HEADS_ + h)) * 32 + chunk) * 4096;
#pragma unroll
  for (int i = 0; i < 4; ++i) {
    float4 v;
    v.x = acc[i][0]; v.y = acc[i][1]; v.z = acc[i][2]; v.w = acc[i][3];
    *(float4*)(op + (rc * 4 + i) * 64 + dc * 4) = v;
  }
}

// ---------------------------------------------------------------------------
// Standalone K1 (first group).
// ---------------------------------------------------------------------------
__global__ __launch_bounds__(256, 2) void k1_mfma(
    const ushort_t* __restrict__ WH, const ushort_t* __restrict__ WL,
    const float* __restrict__ x, const float* __restrict__ gb1,
    const float* __restrict__ gw2, const float* __restrict__ gb2,
    float* __restrict__ qkvraw, float* __restrict__ gpart, int bbase)
{
  __shared__ __align__(16) unsigned char lds[65536];
  k1_body(lds, threadIdx.x, blockIdx.x, blockIdx.y, blockIdx.z,
          WH, WL, x, gb1, gw2, gb2, qkvraw, gpart, bbase);
}

// ---------------------------------------------------------------------------
// Standalone K3b (last group).
// ---------------------------------------------------------------------------
__global__ __launch_bounds__(256, 2) void k3b_gram(
    const float* __restrict__ uni, float* __restrict__ S_part, int bbase)
{
  __shared__ float qs[64][68];
  __shared__ float ks[64][68];
  k3b_body(qs, ks, threadIdx.x, blockIdx.x, blockIdx.y, blockIdx.z,
           bbase + blockIdx.z, uni, S_part);
}

// ---------------------------------------------------------------------------
// UBER: co-schedules k3b(group g, reads uni) with k1(group g+1, writes
// qkvraw) in ONE launch — disjoint buffers, so k3b's work fills k1's
// barrier-stall bubbles instead of running serially after it.
// Block-id split: first nb*128 blocks -> k3b; rest -> k1.
// ---------------------------------------------------------------------------
__global__ __launch_bounds__(256, 2) void k_uber(
    const ushort_t* __restrict__ WH, const ushort_t* __restrict__ WL,
    const float* __restrict__ x, const float* __restrict__ gb1,
    const float* __restrict__ gw2, const float* __restrict__ gb2,
    float* __restrict__ qkvraw, float* __restrict__ gpart,
    const float* __restrict__ uni, float* __restrict__ S_part,
    int nb, int bbase_k3b, int bbase_k1)
{
  __shared__ __align__(16) unsigned char lds[65536];
  const int t = threadIdx.x;
  const int nk3b = nb * 128;
  int bid = blockIdx.x;
  if (bid < nk3b) {
    const int chunk = bid & 31;
    const int h = (bid >> 5) & 3;
    const int s = bid >> 7;
    float (*qs)[68] = (float(*)[68])lds;
    float (*ks)[68] = (float(*)[68])(lds + 64 * 68 * sizeof(float));
    k3b_body(qs, ks, t, chunk, h, s, bbase_k3b + s, uni, S_part);
  } else {
    bid -= nk3b;
    const int cb = bid & 127;
    const int r = bid >> 7;
    const int rb = r % 7;
    const int s = r / 7;
    k1_body(lds, t, cb, rb, s, WH, WL, x, gb1, gw2, gb2, qkvraw, gpart, bbase_k1);
  }
}

// ---------------------------------------------------------------------------
// K3a: depthwise 3x3 (SAME zero pad), 32-row tiles, vectorized staging
// (R12 verbatim). q,k -> fp32 qdw/kdw (+ ssq partials x4); v -> d_out.
// ---------------------------------------------------------------------------
__global__ __launch_bounds__(256) void k3a_dw(
    const float* __restrict__ qkvraw, const float* __restrict__ wdw,
    float* __restrict__ uni, float* __restrict__ vout,
    float* __restrict__ ssq_part, int bbase)
{
  const int t = threadIdx.x;
  const int ytile = blockIdx.x;  // 0..3
  const int ch = blockIdx.y;
  const int s = blockIdx.z;
  const int b = bbase + s;
  const int y0 = ytile * 32;
  float* qdw = uni + (size_t)s * 512 * HW_;
  float* kdw = qdw + (size_t)DIM_ * HW_;

  __shared__ float sm[34][130];
  const float* in = qkvraw + ((size_t)s * D3_ + ch) * HW_;

  if (t < 34) { sm[t][0] = 0.f; sm[t][129] = 0.f; }
#pragma unroll 2
  for (int i = t; i < 1088; i += 256) {
    const int r = i >> 5;
    const int xq = (i & 31) << 2;
    const int row = y0 - 1 + r;
    float4 v = make_float4(0.f, 0.f, 0.f, 0.f);
    if (row >= 0 && row < IMG_H)
      v = *(const float4*)(in + row * IMG_W + xq);
    sm[r][1 + xq] = v.x; sm[r][2 + xq] = v.y;
    sm[r][3 + xq] = v.z; sm[r][4 + xq] = v.w;
  }
  const float* wp = wdw + ch * 9;
  const float w00 = wp[0], w01 = wp[1], w02 = wp[2],
              w10 = wp[3], w11 = wp[4], w12 = wp[5],
              w20 = wp[6], w21 = wp[7], w22 = wp[8];
  __syncthreads();

  float* outp;
  if (ch < 256)       outp = qdw + (size_t)ch * HW_;
  else if (ch < 512)  outp = kdw + (size_t)(ch - 256) * HW_;
  else                outp = vout + ((size_t)b * DIM_ + (ch - 512)) * HW_;

  float sq = 0.f;
#pragma unroll
  for (int it = 0; it < 16; ++it) {
    const int px = t + it * 256;
    const int yl = px >> 7, xx = px & 127;
    const float a =
      w00 * sm[yl][xx]     + w01 * sm[yl][xx + 1]     + w02 * sm[yl][xx + 2] +
      w10 * sm[yl + 1][xx] + w11 * sm[yl + 1][xx + 1] + w12 * sm[yl + 1][xx + 2] +
      w20 * sm[yl + 2][xx] + w21 * sm[yl + 2][xx + 1] + w22 * sm[yl + 2][xx + 2];
    outp[y0 * IMG_W + px] = a;
    sq += a * a;
  }

  if (ch < 512) {
    __shared__ float red[256];
    red[t] = sq;
    __syncthreads();
    for (int o = 128; o > 0; o >>= 1) {
      if (t < o) red[t] += red[t + o];
      __syncthreads();
    }
    if (t == 0) ssq_part[((size_t)b * 512 + ch) * 4 + ytile] = red[0];
  }
}

// ---------------------------------------------------------------------------
// K4: finalize attention (k3c merged in: 32-chunk S_part reduce into LDS).
// 256 threads (4 waves) per (b,h).
// ---------------------------------------------------------------------------
__global__ __launch_bounds__(256) void k4_final(
    const float* __restrict__ S_part, const float* __restrict__ ssq_part,
    const float* __restrict__ gpart, const float* __restrict__ temperature,
    const float* __restrict__ a1, const float* __restrict__ a2,
    const float* __restrict__ a3, const float* __restrict__ a4,
    float* __restrict__ attn)
{
  const int t = threadIdx.x;
  const int lane = t & 63, w = t >> 6;
  const int bh = blockIdx.x;
  const int b = bh >> 2, h = bh & 3;

  __shared__ float Ss[4096];
  __shared__ float red[256];
  __shared__ float invq[64], invk[64];

  // reduce 32 chunk-partials (coalesced)
  for (int i = 0; i < 16; ++i) {
    const int e = i * 256 + t;
    float sum = 0.f;
#pragma unroll 8
    for (int c = 0; c < 32; ++c)
      sum += S_part[((size_t)bh * 32 + c) * 4096 + e];
    Ss[e] = sum;
  }

  red[t] = gpart[t] + gpart[t + 256] + gpart[t + 512] + gpart[t + 768];
  __syncthreads();
  for (int o = 128; o > 0; o >>= 1) {
    if (t < o) red[t] += red[t + o];
    __syncthreads();
  }
  const float mean = red[0] / (float)((size_t)B_ * HW_);
  int dk = (int)floorf((float)C_ * mean);
  dk = min(max(dk, 1), 64);

  if (t < 128) {
    const int d = t & 63;
    const int ch = (t < 64 ? 0 : 256) + h * 64 + d;
    const float* pp = ssq_part + ((size_t)b * 512 + ch) * 4;
    const float sv = pp[0] + pp[1] + pp[2] + pp[3];
    const float inv = 1.f / fmaxf(sqrtf(sv), 1e-12f);
    if (t < 64) invq[d] = inv; else invk[d] = inv;
  }
  __syncthreads();

  const float tval = temperature[h];
  const float ascale = a1[0] + a2[0] + a3[0] + a4[0];
  float* op = attn + (size_t)bh * 4096;

  for (int i = 0; i < 16; ++i) {
    const int c = w * 16 + i;
    const float val = Ss[c * 64 + lane] * invq[c] * invk[lane] * tval;
    int rank = 0;
    for (int j = 0; j < 64; ++j) {
      const float vj = __shfl(val, j, 64);
      rank += ((vj > val) || (vj == val && j < lane)) ? 1 : 0;
    }
    const bool keep = rank < dk;
    float mv = keep ? val : -INFINITY;
#pragma unroll
    for (int m = 1; m < 64; m <<= 1) mv = fmaxf(mv, __shfl_xor(mv, m, 64));
    const float e = keep ? expf(val - mv) : 0.f;
    float ssum = e;
#pragma unroll
    for (int m = 1; m < 64; m <<= 1) ssum += __shfl_xor(ssum, m, 64);
    op[c * 64 + lane] = (e / ssum) * ascale;
  }
}

// ---------------------------------------------------------------------------
// K5: out = attn @ v in place on d_out. LDS-staged v tile [64][128] + attn.
// ---------------------------------------------------------------------------
__global__ __launch_bounds__(256) void k5_av(
    const float* __restrict__ attn, float* __restrict__ out)
{
  const int t = threadIdx.x;
  const int pc = blockIdx.x;  // 0..127
  const int h = blockIdx.y;
  const int b = blockIdx.z;
  const int p0 = pc * 128;

  __shared__ float vs[64][128];   // 32 KB
  __shared__ float As5[64][64];   // 16 KB

  const float* ap = attn + ((size_t)(b * HEADS_ + h)) * 4096;
  float* As5f = &As5[0][0];
#pragma unroll
  for (int j = 0; j < 4; ++j) {
    const int idx = t * 4 + j * 1024;
    *(float4*)&As5f[idx] = *(const float4*)(ap + idx);
  }

  float* base = out + ((size_t)b * DIM_ + h * 64) * HW_ + p0;
#pragma unroll
  for (int k = 0; k < 8; ++k) {
    const int fi = (t + k * 256) * 4;
    const int r = fi >> 7, c = fi & 127;
    *(float4*)&vs[r][c] = *(const float4*)(base + (size_t)r * HW_ + c);
  }
  __syncthreads();

  const int px4 = (t & 31) * 4;
  const int ch0 = (t >> 5) * 8;

  float4 acc[8];
#pragma unroll
  for (int ci = 0; ci < 8; ++ci) acc[ci] = make_float4(0.f, 0.f, 0.f, 0.f);

#pragma unroll 4
  for (int d = 0; d < 64; ++d) {
    const float4 v4 = *(const float4*)&vs[d][px4];
#pragma unroll
    for (int ci = 0; ci < 8; ++ci) {
      const float a = As5[ch0 + ci][d];
      acc[ci].x = fmaf(a, v4.x, acc[ci].x);
      acc[ci].y = fmaf(a, v4.y, acc[ci].y);
      acc[ci].z = fmaf(a, v4.z, acc[ci].z);
      acc[ci].w = fmaf(a, v4.w, acc[ci].w);
    }
  }

#pragma unroll
  for (int ci = 0; ci < 8; ++ci)
    *(float4*)(base + (size_t)(ch0 + ci) * HW_ + px4) = acc[ci];
}

// ---------------------------------------------------------------------------
extern "C" void kernel_launch(void* const* d_in, const int* in_sizes, int n_in,
                              void* d_out, int out_size, void* d_ws, size_t ws_size,
                              hipStream_t stream)
{
  const float* x    = (const float*)d_in[0];
  const float* wqkv = (const float*)d_in[1];
  const float* wdw  = (const float*)d_in[2];
  const float* temp = (const float*)d_in[3];
  const float* a1   = (const float*)d_in[4];
  const float* a2   = (const float*)d_in[5];
  const float* a3   = (const float*)d_in[6];
  const float* a4   = (const float*)d_in[7];
  const float* gw1  = (const float*)d_in[8];
  const float* gb1  = (const float*)d_in[9];
  const float* gw2  = (const float*)d_in[10];
  const float* gb2  = (const float*)d_in[11];
  float* out = (float*)d_out;
  (void)in_sizes; (void)n_in; (void)out_size;

  const size_t HWs = (size_t)HW_;
  // per-slot: qkvraw (768 f) + qdw,kdw fp32 (512 f)
  const size_t perb_f = (size_t)1280 * HWs;
  const size_t fixed_f = (size_t)32 * 32 * 4096
                       + (size_t)8 * 512 * 4
                       + 1024
                       + (size_t)32 * 4096
                       + (size_t)2 * 896 * 256 / 2 + 64;
  int NB = 8;
  while (NB > 1) {
    if ((perb_f * (size_t)NB + fixed_f) * 4 <= ws_size) break;
    NB >>= 1;
  }

  float* ws = (float*)d_ws;
  size_t off = 0;
  float* qkvraw = ws + off; off += (size_t)NB * D3_ * HWs;
  float* uni    = ws + off; off += (size_t)NB * 512 * HWs;
  float* S_part = ws + off; off += (size_t)32 * 32 * 4096;
  float* ssqp   = ws + off; off += (size_t)8 * 512 * 4;
  float* gpart  = ws + off; off += 1024;
  float* attnb  = ws + off; off += (size_t)32 * 4096;
  ushort_t* WH  = (ushort_t*)(ws + off);
  ushort_t* WL  = WH + (size_t)896 * 256;

  k0_wsplit<<<dim3(896), 256, 0, stream>>>(wqkv, gw1, WH, WL);

  const int G = B_ / NB;
  for (int g = 0; g < G; ++g) {
    const int bbase = g * NB;
    if (g == 0)
      k1_mfma<<<dim3(128, 7, NB), 256, 0, stream>>>(WH, WL, x, gb1, gw2, gb2,
                                                    qkvraw, gpart, bbase);
    k3a_dw<<<dim3(4, 768, NB), 256, 0, stream>>>(qkvraw, wdw, uni, out, ssqp, bbase);
    if (g + 1 < G) {
      // co-schedule: k3b(group g) + k1(group g+1) — disjoint buffers
      k_uber<<<dim3(NB * 1024), 256, 0, stream>>>(
          WH, WL, x, gb1, gw2, gb2, qkvraw, gpart, uni, S_part,
          NB, bbase, bbase + NB);
    } else {
      k3b_gram<<<dim3(32, 4, NB), 256, 0, stream>>>(uni, S_part, bbase);
    }
  }
  k4_final<<<dim3(32), 256, 0, stream>>>(S_part, ssqp, gpart, temp,
                                         a1, a2, a3, a4, attnb);
  k5_av<<<dim3(128, 4, 8), 256, 0, stream>>>(attnb, out);
}

// Round 14
// 652.975 us; speedup vs baseline: 1.0085x; 1.0085x over previous
//
#include <hip/hip_runtime.h>
#include <hip/hip_bf16.h>
#include <cmath>

#define HW_ 16384
#define IMG_W 128
#define IMG_H 128
#define DIM_ 256
#define D3_ 768
#define HEADS_ 4
#define C_ 64
#define B_ 8

typedef unsigned short ushort_t;
typedef __attribute__((ext_vector_type(8))) short short8v;
typedef __attribute__((ext_vector_type(16))) float f32x16;

#define GLL16(gp, lp) __builtin_amdgcn_global_load_lds( \
    (const __attribute__((address_space(1))) void*)(gp), \
    (__attribute__((address_space(3))) void*)(lp), 16, 0, 0)

static __device__ __forceinline__ ushort_t f2bf_bits(float v) {
  __hip_bfloat16 h = __float2bfloat16(v);   // RNE — must match k0_wsplit
  return *reinterpret_cast<ushort_t*>(&h);
}
static __device__ __forceinline__ float bf2f(ushort_t u) {
  return __uint_as_float(((unsigned int)u) << 16);
}

// ---------------------------------------------------------------------------
// K0a: split W (w_qkv rows 0..767, gw1 rows 768..895) into bf16 hi/lo (RNE).
// ---------------------------------------------------------------------------
__global__ __launch_bounds__(256) void k0_wsplit(
    const float* __restrict__ wqkv, const float* __restrict__ gw1,
    ushort_t* __restrict__ WH, ushort_t* __restrict__ WL)
{
  const int row = blockIdx.x;
  const int t = threadIdx.x;
  const float* src = (row < 768) ? (wqkv + (size_t)row * DIM_)
                                 : (gw1 + (size_t)(row - 768) * DIM_);
  const float v = src[t];
  const ushort_t hb = f2bf_bits(v);
  WH[(size_t)row * DIM_ + t] = hb;
  WL[(size_t)row * DIM_ + t] = f2bf_bits(v - bf2f(hb));
}

// ---------------------------------------------------------------------------
// K1: MFMA GEMM (bf16 hi/lo, 3 MFMA/product) — R10/R12 verbatim (best
// measured: 132 µs/dispatch). 2-phase, BK=32, 64KB LDS, 1x4 wave grid.
// Rows 0..767 -> qkvraw; rows 768..895 -> fused gate partial sums.
// ---------------------------------------------------------------------------
__global__ __launch_bounds__(256, 2) void k1_mfma(
    const ushort_t* __restrict__ WH, const ushort_t* __restrict__ WL,
    const float* __restrict__ x, const float* __restrict__ gb1,
    const float* __restrict__ gw2, const float* __restrict__ gb2,
    float* __restrict__ qkvraw, float* __restrict__ gpart, int bbase)
{
  const int t = threadIdx.x;
  const int cb = blockIdx.x, rb = blockIdx.y, s = blockIdx.z;
  const int row0 = rb * 128, col0 = cb * 128;
  const float* xb = x + (size_t)(bbase + s) * DIM_ * HW_;

  __shared__ __align__(16) unsigned char lds[65536];
  ushort_t* ldsA = (ushort_t*)lds;                  // [2][8192] shorts
  float*    ldsB = (float*)(lds + 32768);           // [2][4096] floats

  const int lane = t & 63, wid = t >> 6;
  const int rr = lane & 31, lh = lane >> 5;

  const size_t arowb = (size_t)(row0 + wid * 32 + rr) * DIM_;

  f32x16 acc[4];
#pragma unroll
  for (int mi = 0; mi < 4; ++mi)
#pragma unroll
    for (int r = 0; r < 16; ++r) acc[mi][r] = 0.f;

  auto STAGE = [&](int pb, int kt) {
    ushort_t* abase = ldsA + pb * 8192;
#pragma unroll
    for (int i = 0; i < 2; ++i) {
      const int koff = kt * 32 + i * 16 + lh * 8;
      ushort_t* dst = abase + (wid * 2 + i) * 512;  // wave-uniform
      GLL16(WH + arowb + koff, dst);
      GLL16(WL + arowb + koff, dst + 4096);
    }
    float* bbase = ldsB + pb * 4096;
#pragma unroll
    for (int j = 0; j < 4; ++j) {
      const int crow = wid * 8 + j * 2 + lh;        // c within 32
      const float* src = xb + (size_t)(kt * 32 + crow) * HW_ + col0 + rr * 4;
      GLL16(src, bbase + (wid * 8 + j * 2) * 128);  // wave-uniform
    }
  };

  auto COMPUTE = [&](int pb) {
    const ushort_t* pAH = ldsA + pb * 8192;
    const ushort_t* pAL = pAH + 4096;
    const float* bx = ldsB + pb * 4096;
    const int lo = lane * 8;
    const int pidx = wid * 32 + rr;                 // this wave's p column
#pragma unroll
    for (int ks = 0; ks < 2; ++ks) {
      short8v ah[4], al[4];
#pragma unroll
      for (int mi = 0; mi < 4; ++mi) {
        const int base = mi * 1024 + ks * 512 + lo;
        ah[mi] = *(const short8v*)(pAH + base);
        al[mi] = *(const short8v*)(pAL + base);
      }
      short8v bh, bl;
#pragma unroll
      for (int j = 0; j < 8; ++j) {
        const float fv = bx[(ks * 16 + lh * 8 + j) * 128 + pidx];
        const ushort_t hb = f2bf_bits(fv);            // RNE hi
        bh[j] = (short)hb;
        bl[j] = (short)f2bf_bits(fv - bf2f(hb));      // RNE lo
      }
#pragma unroll
      for (int mi = 0; mi < 4; ++mi) {
        acc[mi] = __builtin_amdgcn_mfma_f32_32x32x16_bf16(ah[mi], bh, acc[mi], 0, 0, 0);
        acc[mi] = __builtin_amdgcn_mfma_f32_32x32x16_bf16(ah[mi], bl, acc[mi], 0, 0, 0);
        acc[mi] = __builtin_amdgcn_mfma_f32_32x32x16_bf16(al[mi], bh, acc[mi], 0, 0, 0);
      }
    }
  };

  STAGE(0, 0);
  __syncthreads();

  for (int kt = 0; kt < 8; ++kt) {
    const int pb = kt & 1;
    if (kt < 7) STAGE(pb ^ 1, kt + 1);
    COMPUTE(pb);
    __syncthreads();
  }

  // Epilogue. C/D layout: col=lane&31, row=(reg&3)+8*(reg>>2)+4*(lane>>5)
  const int cl = lane & 31;
  if (rb < 6) {
    const int p = col0 + wid * 32 + cl;
#pragma unroll
    for (int mi = 0; mi < 4; ++mi)
#pragma unroll
      for (int r = 0; r < 16; ++r) {
        const int row = (r & 3) + 8 * (r >> 2) + 4 * lh;
        const int m = row0 + mi * 32 + row;
        qkvraw[((size_t)s * D3_ + m) * HW_ + p] = acc[mi][r];
      }
  } else {
    // fused gate: per-pixel sv = sum_c relu(acc+gb1[c]) * gw2[c]
    float ps = 0.f;
#pragma unroll
    for (int mi = 0; mi < 4; ++mi)
#pragma unroll
      for (int r = 0; r < 16; ++r) {
        const int row = (r & 3) + 8 * (r >> 2) + 4 * lh;
        const int gr = mi * 32 + row;
        ps += fmaxf(acc[mi][r] + gb1[gr], 0.f) * gw2[gr];
      }
    ps += __shfl_xor(ps, 32, 64);
    float* sred = (float*)lds;   // safe: final loop barrier drained all reads
    float* red2 = sred + 128;
    if (lh == 0) sred[wid * 32 + cl] = ps;
    __syncthreads();
    float sig = 0.f;
    if (t < 128) {
      const float sv = sred[t] + gb2[0];
      sig = 1.f / (1.f + expf(-sv));
    }
    __syncthreads();
    red2[t] = sig;
    __syncthreads();
    for (int o = 128; o > 0; o >>= 1) {
      if (t < o) red2[t] += red2[t + o];
      __syncthreads();
    }
    if (t == 0) gpart[(size_t)(bbase + s) * 128 + cb] = red2[0];
  }
}

// ---------------------------------------------------------------------------
// K3a: depthwise 3x3 (SAME zero pad), 32-row tiles, vectorized staging
// (R12 verbatim). q,k -> fp32 qdw/kdw (+ ssq partials x4); v -> d_out.
// ---------------------------------------------------------------------------
__global__ __launch_bounds__(256) void k3a_dw(
    const float* __restrict__ qkvraw, const float* __restrict__ wdw,
    float* __restrict__ uni, float* __restrict__ vout,
    float* __restrict__ ssq_part, int bbase)
{
  const int t = threadIdx.x;
  const int ytile = blockIdx.x;  // 0..3
  const int ch = blockIdx.y;
  const int s = blockIdx.z;
  const int b = bbase + s;
  const int y0 = ytile * 32;
  float* qdw = uni + (size_t)s * 512 * HW_;
  float* kdw = qdw + (size_t)DIM_ * HW_;

  __shared__ float sm[34][130];
  const float* in = qkvraw + ((size_t)s * D3_ + ch) * HW_;

  if (t < 34) { sm[t][0] = 0.f; sm[t][129] = 0.f; }
#pragma unroll 2
  for (int i = t; i < 1088; i += 256) {
    const int r = i >> 5;
    const int xq = (i & 31) << 2;
    const int row = y0 - 1 + r;
    float4 v = make_float4(0.f, 0.f, 0.f, 0.f);
    if (row >= 0 && row < IMG_H)
      v = *(const float4*)(in + row * IMG_W + xq);
    sm[r][1 + xq] = v.x; sm[r][2 + xq] = v.y;
    sm[r][3 + xq] = v.z; sm[r][4 + xq] = v.w;
  }
  const float* wp = wdw + ch * 9;
  const float w00 = wp[0], w01 = wp[1], w02 = wp[2],
              w10 = wp[3], w11 = wp[4], w12 = wp[5],
              w20 = wp[6], w21 = wp[7], w22 = wp[8];
  __syncthreads();

  float* outp;
  if (ch < 256)       outp = qdw + (size_t)ch * HW_;
  else if (ch < 512)  outp = kdw + (size_t)(ch - 256) * HW_;
  else                outp = vout + ((size_t)b * DIM_ + (ch - 512)) * HW_;

  float sq = 0.f;
#pragma unroll
  for (int it = 0; it < 16; ++it) {
    const int px = t + it * 256;
    const int yl = px >> 7, xx = px & 127;
    const float a =
      w00 * sm[yl][xx]     + w01 * sm[yl][xx + 1]     + w02 * sm[yl][xx + 2] +
      w10 * sm[yl + 1][xx] + w11 * sm[yl + 1][xx + 1] + w12 * sm[yl + 1][xx + 2] +
      w20 * sm[yl + 2][xx] + w21 * sm[yl + 2][xx + 1] + w22 * sm[yl + 2][xx + 2];
    outp[y0 * IMG_W + px] = a;
    sq += a * a;
  }

  if (ch < 512) {
    __shared__ float red[256];
    red[t] = sq;
    __syncthreads();
    for (int o = 128; o > 0; o >>= 1) {
      if (t < o) red[t] += red[t + o];
      __syncthreads();
    }
    if (t == 0) ssq_part[((size_t)b * 512 + ch) * 4 + ytile] = red[0];
  }
}

// ---------------------------------------------------------------------------
// K3b: Gram partials over 512-pixel chunks (32 chunks per b,h), fp32 input.
// CHANGE vs R12: XOR group-swizzled LDS layout — (p,c) stored at column
// 4*((c>>2) ^ (p>>2)) + (c&3). Kills the 8-way write conflict (banks
// (16s+c)%32 -> 2-way) and the 8-way k-read conflict (16 addrs over 2
// banks -> 8 banks 2-way). Pure address permutation: values unchanged.
// ---------------------------------------------------------------------------
__global__ __launch_bounds__(256) void k3b_gram(
    const float* __restrict__ uni, float* __restrict__ S_part, int bbase)
{
  const int t = threadIdx.x;
  const int chunk = blockIdx.x;  // 0..31
  const int h = blockIdx.y;
  const int s = blockIdx.z;
  const int b = bbase + s;
  const int p0 = chunk * 512;
  const float* qdw = uni + (size_t)s * 512 * HW_;
  const float* kdw = qdw + (size_t)DIM_ * HW_;

  __shared__ float qs[64][68];
  __shared__ float ks[64][68];

  const int rc = t >> 4, dc = t & 15;

  float acc[4][4];
#pragma unroll
  for (int i = 0; i < 4; ++i)
#pragma unroll
    for (int j = 0; j < 4; ++j) acc[i][j] = 0.f;

  const float* qbase = qdw + (size_t)h * 64 * HW_ + p0;
  const float* kbase = kdw + (size_t)h * 64 * HW_ + p0;

  for (int kk = 0; kk < 512; kk += 64) {
    __syncthreads();
#pragma unroll
    for (int j = 0; j < 4; ++j) {
      const int lin = t + j * 256;
      const int c = lin >> 4;
      const int px0 = (lin & 15) << 2;
      const int cg = c >> 2, cu = c & 3;
      const int pg = lin & 15;              // (px0+i)>>2 for i=0..3
      const int colq = 4 * (cg ^ pg) + cu;  // swizzled column
      const float4 qv = *(const float4*)(qbase + (size_t)c * HW_ + kk + px0);
      const float4 kv = *(const float4*)(kbase + (size_t)c * HW_ + kk + px0);
      qs[px0 + 0][colq] = qv.x; qs[px0 + 1][colq] = qv.y;
      qs[px0 + 2][colq] = qv.z; qs[px0 + 3][colq] = qv.w;
      ks[px0 + 0][colq] = kv.x; ks[px0 + 1][colq] = kv.y;
      ks[px0 + 2][colq] = kv.z; ks[px0 + 3][colq] = kv.w;
    }
    __syncthreads();
#pragma unroll 4
    for (int p = 0; p < 64; ++p) {
      const int pg = p >> 2;
      const float4 q4 = *(const float4*)&qs[p][4 * (rc ^ pg)];
      const float4 k4 = *(const float4*)&ks[p][4 * (dc ^ pg)];
      const float qa[4] = {q4.x, q4.y, q4.z, q4.w};
      const float ka[4] = {k4.x, k4.y, k4.z, k4.w};
#pragma unroll
      for (int i = 0; i < 4; ++i)
#pragma unroll
        for (int jj = 0; jj < 4; ++jj) acc[i][jj] += qa[i] * ka[jj];
    }
  }
  float* op = S_part + (((size_t)(b * HEADS_ + h)) * 32 + chunk) * 4096;
#pragma unroll
  for (int i = 0; i < 4; ++i) {
    float4 v;
    v.x = acc[i][0]; v.y = acc[i][1]; v.z = acc[i][2]; v.w = acc[i][3];
    *(float4*)(op + (rc * 4 + i) * 64 + dc * 4) = v;
  }
}

// ---------------------------------------------------------------------------
// K4: finalize attention (k3c merged: 32-chunk S_part reduce into LDS).
// 256 threads (4 waves) per (b,h).
// ---------------------------------------------------------------------------
__global__ __launch_bounds__(256) void k4_final(
    const float* __restrict__ S_part, const float* __restrict__ ssq_part,
    const float* __restrict__ gpart, const float* __restrict__ temperature,
    const float* __restrict__ a1, const float* __restrict__ a2,
    const float* __restrict__ a3, const float* __restrict__ a4,
    float* __restrict__ attn)
{
  const int t = threadIdx.x;
  const int lane = t & 63, w = t >> 6;
  const int bh = blockIdx.x;
  const int b = bh >> 2, h = bh & 3;

  __shared__ float Ss[4096];
  __shared__ float red[256];
  __shared__ float invq[64], invk[64];

  for (int i = 0; i < 16; ++i) {
    const int e = i * 256 + t;
    float sum = 0.f;
#pragma unroll 8
    for (int c = 0; c < 32; ++c)
      sum += S_part[((size_t)bh * 32 + c) * 4096 + e];
    Ss[e] = sum;
  }

  red[t] = gpart[t] + gpart[t + 256] + gpart[t + 512] + gpart[t + 768];
  __syncthreads();
  for (int o = 128; o > 0; o >>= 1) {
    if (t < o) red[t] += red[t + o];
    __syncthreads();
  }
  const float mean = red[0] / (float)((size_t)B_ * HW_);
  int dk = (int)floorf((float)C_ * mean);
  dk = min(max(dk, 1), 64);

  if (t < 128) {
    const int d = t & 63;
    const int ch = (t < 64 ? 0 : 256) + h * 64 + d;
    const float* pp = ssq_part + ((size_t)b * 512 + ch) * 4;
    const float sv = pp[0] + pp[1] + pp[2] + pp[3];
    const float inv = 1.f / fmaxf(sqrtf(sv), 1e-12f);
    if (t < 64) invq[d] = inv; else invk[d] = inv;
  }
  __syncthreads();

  const float tval = temperature[h];
  const float ascale = a1[0] + a2[0] + a3[0] + a4[0];
  float* op = attn + (size_t)bh * 4096;

  for (int i = 0; i < 16; ++i) {
    const int c = w * 16 + i;
    const float val = Ss[c * 64 + lane] * invq[c] * invk[lane] * tval;
    int rank = 0;
    for (int j = 0; j < 64; ++j) {
      const float vj = __shfl(val, j, 64);
      rank += ((vj > val) || (vj == val && j < lane)) ? 1 : 0;
    }
    const bool keep = rank < dk;
    float mv = keep ? val : -INFINITY;
#pragma unroll
    for (int m = 1; m < 64; m <<= 1) mv = fmaxf(mv, __shfl_xor(mv, m, 64));
    const float e = keep ? expf(val - mv) : 0.f;
    float ssum = e;
#pragma unroll
    for (int m = 1; m < 64; m <<= 1) ssum += __shfl_xor(ssum, m, 64);
    op[c * 64 + lane] = (e / ssum) * ascale;
  }
}

// ---------------------------------------------------------------------------
// K5: out = attn @ v in place on d_out. LDS-staged v tile [64][128] + attn.
// ---------------------------------------------------------------------------
__global__ __launch_bounds__(256) void k5_av(
    const float* __restrict__ attn, float* __restrict__ out)
{
  const int t = threadIdx.x;
  const int pc = blockIdx.x;  // 0..127
  const int h = blockIdx.y;
  const int b = blockIdx.z;
  const int p0 = pc * 128;

  __shared__ float vs[64][128];   // 32 KB
  __shared__ float As5[64][64];   // 16 KB

  const float* ap = attn + ((size_t)(b * HEADS_ + h)) * 4096;
  float* As5f = &As5[0][0];
#pragma unroll
  for (int j = 0; j < 4; ++j) {
    const int idx = t * 4 + j * 1024;
    *(float4*)&As5f[idx] = *(const float4*)(ap + idx);
  }

  float* base = out + ((size_t)b * DIM_ + h * 64) * HW_ + p0;
#pragma unroll
  for (int k = 0; k < 8; ++k) {
    const int fi = (t + k * 256) * 4;
    const int r = fi >> 7, c = fi & 127;
    *(float4*)&vs[r][c] = *(const float4*)(base + (size_t)r * HW_ + c);
  }
  __syncthreads();

  const int px4 = (t & 31) * 4;
  const int ch0 = (t >> 5) * 8;

  float4 acc[8];
#pragma unroll
  for (int ci = 0; ci < 8; ++ci) acc[ci] = make_float4(0.f, 0.f, 0.f, 0.f);

#pragma unroll 4
  for (int d = 0; d < 64; ++d) {
    const float4 v4 = *(const float4*)&vs[d][px4];
#pragma unroll
    for (int ci = 0; ci < 8; ++ci) {
      const float a = As5[ch0 + ci][d];
      acc[ci].x = fmaf(a, v4.x, acc[ci].x);
      acc[ci].y = fmaf(a, v4.y, acc[ci].y);
      acc[ci].z = fmaf(a, v4.z, acc[ci].z);
      acc[ci].w = fmaf(a, v4.w, acc[ci].w);
    }
  }

#pragma unroll
  for (int ci = 0; ci < 8; ++ci)
    *(float4*)(base + (size_t)(ch0 + ci) * HW_ + px4) = acc[ci];
}

// ---------------------------------------------------------------------------
extern "C" void kernel_launch(void* const* d_in, const int* in_sizes, int n_in,
                              void* d_out, int out_size, void* d_ws, size_t ws_size,
                              hipStream_t stream)
{
  const float* x    = (const float*)d_in[0];
  const float* wqkv = (const float*)d_in[1];
  const float* wdw  = (const float*)d_in[2];
  const float* temp = (const float*)d_in[3];
  const float* a1   = (const float*)d_in[4];
  const float* a2   = (const float*)d_in[5];
  const float* a3   = (const float*)d_in[6];
  const float* a4   = (const float*)d_in[7];
  const float* gw1  = (const float*)d_in[8];
  const float* gb1  = (const float*)d_in[9];
  const float* gw2  = (const float*)d_in[10];
  const float* gb2  = (const float*)d_in[11];
  float* out = (float*)d_out;
  (void)in_sizes; (void)n_in; (void)out_size;

  const size_t HWs = (size_t)HW_;
  // per-slot: qkvraw (768 f) + qdw,kdw fp32 (512 f)
  const size_t perb_f = (size_t)1280 * HWs;
  const size_t fixed_f = (size_t)32 * 32 * 4096
                       + (size_t)8 * 512 * 4
                       + 1024
                       + (size_t)32 * 4096
                       + (size_t)2 * 896 * 256 / 2 + 64;
  int NB = 8;
  while (NB > 1) {
    if ((perb_f * (size_t)NB + fixed_f) * 4 <= ws_size) break;
    NB >>= 1;
  }

  float* ws = (float*)d_ws;
  size_t off = 0;
  float* qkvraw = ws + off; off += (size_t)NB * D3_ * HWs;
  float* uni    = ws + off; off += (size_t)NB * 512 * HWs;
  float* S_part = ws + off; off += (size_t)32 * 32 * 4096;
  float* ssqp   = ws + off; off += (size_t)8 * 512 * 4;
  float* gpart  = ws + off; off += 1024;
  float* attnb  = ws + off; off += (size_t)32 * 4096;
  ushort_t* WH  = (ushort_t*)(ws + off);
  ushort_t* WL  = WH + (size_t)896 * 256;

  k0_wsplit<<<dim3(896), 256, 0, stream>>>(wqkv, gw1, WH, WL);

  for (int g = 0; g < B_ / NB; ++g) {
    const int bbase = g * NB;
    k1_mfma<<<dim3(128, 7, NB), 256, 0, stream>>>(WH, WL, x, gb1, gw2, gb2,
                                                  qkvraw, gpart, bbase);
    k3a_dw<<<dim3(4, 768, NB), 256, 0, stream>>>(qkvraw, wdw, uni, out, ssqp, bbase);
    k3b_gram<<<dim3(32, 4, NB), 256, 0, stream>>>(uni, S_part, bbase);
  }
  k4_final<<<dim3(32), 256, 0, stream>>>(S_part, ssqp, gpart, temp,
                                         a1, a2, a3, a4, attnb);
  k5_av<<<dim3(128, 4, 8), 256, 0, stream>>>(attnb, out);
}

// Round 15
// 613.222 us; speedup vs baseline: 1.0738x; 1.0648x over previous
//
#include <hip/hip_runtime.h>
#include <hip/hip_bf16.h>
#include <cmath>

#define HW_ 16384
#define IMG_W 128
#define IMG_H 128
#define DIM_ 256
#define D3_ 768
#define HEADS_ 4
#define C_ 64
#define B_ 8

typedef unsigned short ushort_t;
typedef __attribute__((ext_vector_type(8))) short short8v;
typedef __attribute__((ext_vector_type(16))) float f32x16;

#define GLL16(gp, lp) __builtin_amdgcn_global_load_lds( \
    (const __attribute__((address_space(1))) void*)(gp), \
    (__attribute__((address_space(3))) void*)(lp), 16, 0, 0)

static __device__ __forceinline__ ushort_t f2bf_bits(float v) {
  __hip_bfloat16 h = __float2bfloat16(v);   // RNE — must match k0_wsplit
  return *reinterpret_cast<ushort_t*>(&h);
}
static __device__ __forceinline__ float bf2f(ushort_t u) {
  return __uint_as_float(((unsigned int)u) << 16);
}

// ---------------------------------------------------------------------------
// K0a: split W (w_qkv rows 0..767, gw1 rows 768..895) into bf16 hi/lo (RNE).
// ---------------------------------------------------------------------------
__global__ __launch_bounds__(256) void k0_wsplit(
    const float* __restrict__ wqkv, const float* __restrict__ gw1,
    ushort_t* __restrict__ WH, ushort_t* __restrict__ WL)
{
  const int row = blockIdx.x;
  const int t = threadIdx.x;
  const float* src = (row < 768) ? (wqkv + (size_t)row * DIM_)
                                 : (gw1 + (size_t)(row - 768) * DIM_);
  const float v = src[t];
  const ushort_t hb = f2bf_bits(v);
  WH[(size_t)row * DIM_ + t] = hb;
  WL[(size_t)row * DIM_ + t] = f2bf_bits(v - bf2f(hb));
}

// ---------------------------------------------------------------------------
// K1: MFMA GEMM (bf16 hi/lo, 3 MFMA/product) — R10/R12 verbatim (best
// measured: 132 µs/dispatch). 2-phase, BK=32, 64KB LDS, 1x4 wave grid.
// Rows 0..767 -> qkvraw; rows 768..895 -> fused gate partial sums.
// ---------------------------------------------------------------------------
__global__ __launch_bounds__(256, 2) void k1_mfma(
    const ushort_t* __restrict__ WH, const ushort_t* __restrict__ WL,
    const float* __restrict__ x, const float* __restrict__ gb1,
    const float* __restrict__ gw2, const float* __restrict__ gb2,
    float* __restrict__ qkvraw, float* __restrict__ gpart, int bbase)
{
  const int t = threadIdx.x;
  const int cb = blockIdx.x, rb = blockIdx.y, s = blockIdx.z;
  const int row0 = rb * 128, col0 = cb * 128;
  const float* xb = x + (size_t)(bbase + s) * DIM_ * HW_;

  __shared__ __align__(16) unsigned char lds[65536];
  ushort_t* ldsA = (ushort_t*)lds;                  // [2][8192] shorts
  float*    ldsB = (float*)(lds + 32768);           // [2][4096] floats

  const int lane = t & 63, wid = t >> 6;
  const int rr = lane & 31, lh = lane >> 5;

  const size_t arowb = (size_t)(row0 + wid * 32 + rr) * DIM_;

  f32x16 acc[4];
#pragma unroll
  for (int mi = 0; mi < 4; ++mi)
#pragma unroll
    for (int r = 0; r < 16; ++r) acc[mi][r] = 0.f;

  auto STAGE = [&](int pb, int kt) {
    ushort_t* abase = ldsA + pb * 8192;
#pragma unroll
    for (int i = 0; i < 2; ++i) {
      const int koff = kt * 32 + i * 16 + lh * 8;
      ushort_t* dst = abase + (wid * 2 + i) * 512;  // wave-uniform
      GLL16(WH + arowb + koff, dst);
      GLL16(WL + arowb + koff, dst + 4096);
    }
    float* bbase = ldsB + pb * 4096;
#pragma unroll
    for (int j = 0; j < 4; ++j) {
      const int crow = wid * 8 + j * 2 + lh;        // c within 32
      const float* src = xb + (size_t)(kt * 32 + crow) * HW_ + col0 + rr * 4;
      GLL16(src, bbase + (wid * 8 + j * 2) * 128);  // wave-uniform
    }
  };

  auto COMPUTE = [&](int pb) {
    const ushort_t* pAH = ldsA + pb * 8192;
    const ushort_t* pAL = pAH + 4096;
    const float* bx = ldsB + pb * 4096;
    const int lo = lane * 8;
    const int pidx = wid * 32 + rr;                 // this wave's p column
#pragma unroll
    for (int ks = 0; ks < 2; ++ks) {
      short8v ah[4], al[4];
#pragma unroll
      for (int mi = 0; mi < 4; ++mi) {
        const int base = mi * 1024 + ks * 512 + lo;
        ah[mi] = *(const short8v*)(pAH + base);
        al[mi] = *(const short8v*)(pAL + base);
      }
      short8v bh, bl;
#pragma unroll
      for (int j = 0; j < 8; ++j) {
        const float fv = bx[(ks * 16 + lh * 8 + j) * 128 + pidx];
        const ushort_t hb = f2bf_bits(fv);            // RNE hi
        bh[j] = (short)hb;
        bl[j] = (short)f2bf_bits(fv - bf2f(hb));      // RNE lo
      }
#pragma unroll
      for (int mi = 0; mi < 4; ++mi) {
        acc[mi] = __builtin_amdgcn_mfma_f32_32x32x16_bf16(ah[mi], bh, acc[mi], 0, 0, 0);
        acc[mi] = __builtin_amdgcn_mfma_f32_32x32x16_bf16(ah[mi], bl, acc[mi], 0, 0, 0);
        acc[mi] = __builtin_amdgcn_mfma_f32_32x32x16_bf16(al[mi], bh, acc[mi], 0, 0, 0);
      }
    }
  };

  STAGE(0, 0);
  __syncthreads();

  for (int kt = 0; kt < 8; ++kt) {
    const int pb = kt & 1;
    if (kt < 7) STAGE(pb ^ 1, kt + 1);
    COMPUTE(pb);
    __syncthreads();
  }

  // Epilogue. C/D layout: col=lane&31, row=(reg&3)+8*(reg>>2)+4*(lane>>5)
  const int cl = lane & 31;
  if (rb < 6) {
    const int p = col0 + wid * 32 + cl;
#pragma unroll
    for (int mi = 0; mi < 4; ++mi)
#pragma unroll
      for (int r = 0; r < 16; ++r) {
        const int row = (r & 3) + 8 * (r >> 2) + 4 * lh;
        const int m = row0 + mi * 32 + row;
        qkvraw[((size_t)s * D3_ + m) * HW_ + p] = acc[mi][r];
      }
  } else {
    // fused gate: per-pixel sv = sum_c relu(acc+gb1[c]) * gw2[c]
    float ps = 0.f;
#pragma unroll
    for (int mi = 0; mi < 4; ++mi)
#pragma unroll
      for (int r = 0; r < 16; ++r) {
        const int row = (r & 3) + 8 * (r >> 2) + 4 * lh;
        const int gr = mi * 32 + row;
        ps += fmaxf(acc[mi][r] + gb1[gr], 0.f) * gw2[gr];
      }
    ps += __shfl_xor(ps, 32, 64);
    float* sred = (float*)lds;   // safe: final loop barrier drained all reads
    float* red2 = sred + 128;
    if (lh == 0) sred[wid * 32 + cl] = ps;
    __syncthreads();
    float sig = 0.f;
    if (t < 128) {
      const float sv = sred[t] + gb2[0];
      sig = 1.f / (1.f + expf(-sv));
    }
    __syncthreads();
    red2[t] = sig;
    __syncthreads();
    for (int o = 128; o > 0; o >>= 1) {
      if (t < o) red2[t] += red2[t + o];
      __syncthreads();
    }
    if (t == 0) gpart[(size_t)(bbase + s) * 128 + cb] = red2[0];
  }
}

// ---------------------------------------------------------------------------
// K3a: depthwise 3x3 (SAME zero pad), 32-row tiles, vectorized staging
// (R12 verbatim). q,k -> fp32 qdw/kdw (+ ssq partials x4); v -> d_out.
// ---------------------------------------------------------------------------
__global__ __launch_bounds__(256) void k3a_dw(
    const float* __restrict__ qkvraw, const float* __restrict__ wdw,
    float* __restrict__ uni, float* __restrict__ vout,
    float* __restrict__ ssq_part, int bbase)
{
  const int t = threadIdx.x;
  const int ytile = blockIdx.x;  // 0..3
  const int ch = blockIdx.y;
  const int s = blockIdx.z;
  const int b = bbase + s;
  const int y0 = ytile * 32;
  float* qdw = uni + (size_t)s * 512 * HW_;
  float* kdw = qdw + (size_t)DIM_ * HW_;

  __shared__ float sm[34][130];
  const float* in = qkvraw + ((size_t)s * D3_ + ch) * HW_;

  if (t < 34) { sm[t][0] = 0.f; sm[t][129] = 0.f; }
#pragma unroll 2
  for (int i = t; i < 1088; i += 256) {
    const int r = i >> 5;
    const int xq = (i & 31) << 2;
    const int row = y0 - 1 + r;
    float4 v = make_float4(0.f, 0.f, 0.f, 0.f);
    if (row >= 0 && row < IMG_H)
      v = *(const float4*)(in + row * IMG_W + xq);
    sm[r][1 + xq] = v.x; sm[r][2 + xq] = v.y;
    sm[r][3 + xq] = v.z; sm[r][4 + xq] = v.w;
  }
  const float* wp = wdw + ch * 9;
  const float w00 = wp[0], w01 = wp[1], w02 = wp[2],
              w10 = wp[3], w11 = wp[4], w12 = wp[5],
              w20 = wp[6], w21 = wp[7], w22 = wp[8];
  __syncthreads();

  float* outp;
  if (ch < 256)       outp = qdw + (size_t)ch * HW_;
  else if (ch < 512)  outp = kdw + (size_t)(ch - 256) * HW_;
  else                outp = vout + ((size_t)b * DIM_ + (ch - 512)) * HW_;

  float sq = 0.f;
#pragma unroll
  for (int it = 0; it < 16; ++it) {
    const int px = t + it * 256;
    const int yl = px >> 7, xx = px & 127;
    const float a =
      w00 * sm[yl][xx]     + w01 * sm[yl][xx + 1]     + w02 * sm[yl][xx + 2] +
      w10 * sm[yl + 1][xx] + w11 * sm[yl + 1][xx + 1] + w12 * sm[yl + 1][xx + 2] +
      w20 * sm[yl + 2][xx] + w21 * sm[yl + 2][xx + 1] + w22 * sm[yl + 2][xx + 2];
    outp[y0 * IMG_W + px] = a;
    sq += a * a;
  }

  if (ch < 512) {
    __shared__ float red[256];
    red[t] = sq;
    __syncthreads();
    for (int o = 128; o > 0; o >>= 1) {
      if (t < o) red[t] += red[t + o];
      __syncthreads();
    }
    if (t == 0) ssq_part[((size_t)b * 512 + ch) * 4 + ytile] = red[0];
  }
}

// ---------------------------------------------------------------------------
// K3b: Gram partials over 512-pixel chunks (32 chunks per b,h), fp32 input.
// XOR group-swizzled LDS layout (R14): (p,c) stored at column
// 4*((c>>2)^(p>>2)) + (c&3) — kills the 8-way write & read conflicts.
// Pure address permutation: values unchanged.
// ---------------------------------------------------------------------------
__global__ __launch_bounds__(256) void k3b_gram(
    const float* __restrict__ uni, float* __restrict__ S_part, int bbase)
{
  const int t = threadIdx.x;
  const int chunk = blockIdx.x;  // 0..31
  const int h = blockIdx.y;
  const int s = blockIdx.z;
  const int b = bbase + s;
  const int p0 = chunk * 512;
  const float* qdw = uni + (size_t)s * 512 * HW_;
  const float* kdw = qdw + (size_t)DIM_ * HW_;

  __shared__ float qs[64][68];
  __shared__ float ks[64][68];

  const int rc = t >> 4, dc = t & 15;

  float acc[4][4];
#pragma unroll
  for (int i = 0; i < 4; ++i)
#pragma unroll
    for (int j = 0; j < 4; ++j) acc[i][j] = 0.f;

  const float* qbase = qdw + (size_t)h * 64 * HW_ + p0;
  const float* kbase = kdw + (size_t)h * 64 * HW_ + p0;

  for (int kk = 0; kk < 512; kk += 64) {
    __syncthreads();
#pragma unroll
    for (int j = 0; j < 4; ++j) {
      const int lin = t + j * 256;
      const int c = lin >> 4;
      const int px0 = (lin & 15) << 2;
      const int cg = c >> 2, cu = c & 3;
      const int pg = lin & 15;              // (px0+i)>>2 for i=0..3
      const int colq = 4 * (cg ^ pg) + cu;  // swizzled column
      const float4 qv = *(const float4*)(qbase + (size_t)c * HW_ + kk + px0);
      const float4 kv = *(const float4*)(kbase + (size_t)c * HW_ + kk + px0);
      qs[px0 + 0][colq] = qv.x; qs[px0 + 1][colq] = qv.y;
      qs[px0 + 2][colq] = qv.z; qs[px0 + 3][colq] = qv.w;
      ks[px0 + 0][colq] = kv.x; ks[px0 + 1][colq] = kv.y;
      ks[px0 + 2][colq] = kv.z; ks[px0 + 3][colq] = kv.w;
    }
    __syncthreads();
#pragma unroll 4
    for (int p = 0; p < 64; ++p) {
      const int pg = p >> 2;
      const float4 q4 = *(const float4*)&qs[p][4 * (rc ^ pg)];
      const float4 k4 = *(const float4*)&ks[p][4 * (dc ^ pg)];
      const float qa[4] = {q4.x, q4.y, q4.z, q4.w};
      const float ka[4] = {k4.x, k4.y, k4.z, k4.w};
#pragma unroll
      for (int i = 0; i < 4; ++i)
#pragma unroll
        for (int jj = 0; jj < 4; ++jj) acc[i][jj] += qa[i] * ka[jj];
    }
  }
  float* op = S_part + (((size_t)(b * HEADS_ + h)) * 32 + chunk) * 4096;
#pragma unroll
  for (int i = 0; i < 4; ++i) {
    float4 v;
    v.x = acc[i][0]; v.y = acc[i][1]; v.z = acc[i][2]; v.w = acc[i][3];
    *(float4*)(op + (rc * 4 + i) * 64 + dc * 4) = v;
  }
}

// ---------------------------------------------------------------------------
// K3c: parallel reduce S_part[32 chunks] -> S. 512 blocks, fully coalesced.
// ---------------------------------------------------------------------------
__global__ __launch_bounds__(256) void k3c_reduce(
    const float* __restrict__ S_part, float* __restrict__ S)
{
  const int t = threadIdx.x;
  const int bh = blockIdx.y;
  const int e = blockIdx.x * 256 + t;
  float sum = 0.f;
#pragma unroll 8
  for (int c = 0; c < 32; ++c)
    sum += S_part[((size_t)bh * 32 + c) * 4096 + e];
  S[(size_t)bh * 4096 + e] = sum;
}

// ---------------------------------------------------------------------------
// K4: finalize attention (R12 form). 256 threads (4 waves) per (b,h).
// ---------------------------------------------------------------------------
__global__ __launch_bounds__(256) void k4_final(
    const float* __restrict__ S, const float* __restrict__ ssq_part,
    const float* __restrict__ gpart, const float* __restrict__ temperature,
    const float* __restrict__ a1, const float* __restrict__ a2,
    const float* __restrict__ a3, const float* __restrict__ a4,
    float* __restrict__ attn)
{
  const int t = threadIdx.x;
  const int lane = t & 63, w = t >> 6;
  const int bh = blockIdx.x;
  const int b = bh >> 2, h = bh & 3;

  __shared__ float red[256];
  __shared__ float invq[64], invk[64];

  red[t] = gpart[t] + gpart[t + 256] + gpart[t + 512] + gpart[t + 768];
  __syncthreads();
  for (int o = 128; o > 0; o >>= 1) {
    if (t < o) red[t] += red[t + o];
    __syncthreads();
  }
  const float mean = red[0] / (float)((size_t)B_ * HW_);
  int dk = (int)floorf((float)C_ * mean);
  dk = min(max(dk, 1), 64);

  if (t < 128) {
    const int d = t & 63;
    const int ch = (t < 64 ? 0 : 256) + h * 64 + d;
    const float* pp = ssq_part + ((size_t)b * 512 + ch) * 4;
    const float sv = pp[0] + pp[1] + pp[2] + pp[3];
    const float inv = 1.f / fmaxf(sqrtf(sv), 1e-12f);
    if (t < 64) invq[d] = inv; else invk[d] = inv;
  }
  __syncthreads();

  const float tval = temperature[h];
  const float ascale = a1[0] + a2[0] + a3[0] + a4[0];
  const float* Sp = S + (size_t)bh * 4096;
  float* op = attn + (size_t)bh * 4096;

  for (int i = 0; i < 16; ++i) {
    const int c = w * 16 + i;
    const float val = Sp[c * 64 + lane] * invq[c] * invk[lane] * tval;
    int rank = 0;
    for (int j = 0; j < 64; ++j) {
      const float vj = __shfl(val, j, 64);
      rank += ((vj > val) || (vj == val && j < lane)) ? 1 : 0;
    }
    const bool keep = rank < dk;
    float mv = keep ? val : -INFINITY;
#pragma unroll
    for (int m = 1; m < 64; m <<= 1) mv = fmaxf(mv, __shfl_xor(mv, m, 64));
    const float e = keep ? expf(val - mv) : 0.f;
    float ssum = e;
#pragma unroll
    for (int m = 1; m < 64; m <<= 1) ssum += __shfl_xor(ssum, m, 64);
    op[c * 64 + lane] = (e / ssum) * ascale;
  }
}

// ---------------------------------------------------------------------------
// K5: out = attn @ v in place on d_out. LDS-staged v tile [64][128] + attn.
// ---------------------------------------------------------------------------
__global__ __launch_bounds__(256) void k5_av(
    const float* __restrict__ attn, float* __restrict__ out)
{
  const int t = threadIdx.x;
  const int pc = blockIdx.x;  // 0..127
  const int h = blockIdx.y;
  const int b = blockIdx.z;
  const int p0 = pc * 128;

  __shared__ float vs[64][128];   // 32 KB
  __shared__ float As5[64][64];   // 16 KB

  const float* ap = attn + ((size_t)(b * HEADS_ + h)) * 4096;
  float* As5f = &As5[0][0];
#pragma unroll
  for (int j = 0; j < 4; ++j) {
    const int idx = t * 4 + j * 1024;
    *(float4*)&As5f[idx] = *(const float4*)(ap + idx);
  }

  float* base = out + ((size_t)b * DIM_ + h * 64) * HW_ + p0;
#pragma unroll
  for (int k = 0; k < 8; ++k) {
    const int fi = (t + k * 256) * 4;
    const int r = fi >> 7, c = fi & 127;
    *(float4*)&vs[r][c] = *(const float4*)(base + (size_t)r * HW_ + c);
  }
  __syncthreads();

  const int px4 = (t & 31) * 4;
  const int ch0 = (t >> 5) * 8;

  float4 acc[8];
#pragma unroll
  for (int ci = 0; ci < 8; ++ci) acc[ci] = make_float4(0.f, 0.f, 0.f, 0.f);

#pragma unroll 4
  for (int d = 0; d < 64; ++d) {
    const float4 v4 = *(const float4*)&vs[d][px4];
#pragma unroll
    for (int ci = 0; ci < 8; ++ci) {
      const float a = As5[ch0 + ci][d];
      acc[ci].x = fmaf(a, v4.x, acc[ci].x);
      acc[ci].y = fmaf(a, v4.y, acc[ci].y);
      acc[ci].z = fmaf(a, v4.z, acc[ci].z);
      acc[ci].w = fmaf(a, v4.w, acc[ci].w);
    }
  }

#pragma unroll
  for (int ci = 0; ci < 8; ++ci)
    *(float4*)(base + (size_t)(ch0 + ci) * HW_ + px4) = acc[ci];
}

// ---------------------------------------------------------------------------
extern "C" void kernel_launch(void* const* d_in, const int* in_sizes, int n_in,
                              void* d_out, int out_size, void* d_ws, size_t ws_size,
                              hipStream_t stream)
{
  const float* x    = (const float*)d_in[0];
  const float* wqkv = (const float*)d_in[1];
  const float* wdw  = (const float*)d_in[2];
  const float* temp = (const float*)d_in[3];
  const float* a1   = (const float*)d_in[4];
  const float* a2   = (const float*)d_in[5];
  const float* a3   = (const float*)d_in[6];
  const float* a4   = (const float*)d_in[7];
  const float* gw1  = (const float*)d_in[8];
  const float* gb1  = (const float*)d_in[9];
  const float* gw2  = (const float*)d_in[10];
  const float* gb2  = (const float*)d_in[11];
  float* out = (float*)d_out;
  (void)in_sizes; (void)n_in; (void)out_size;

  const size_t HWs = (size_t)HW_;
  // per-slot: qkvraw (768 f) + qdw,kdw fp32 (512 f)
  const size_t perb_f = (size_t)1280 * HWs;
  const size_t fixed_f = (size_t)32 * 32 * 4096
                       + (size_t)32 * 4096
                       + (size_t)8 * 512 * 4
                       + 1024
                       + (size_t)32 * 4096
                       + (size_t)2 * 896 * 256 / 2 + 64;
  int NB = 8;
  while (NB > 1) {
    if ((perb_f * (size_t)NB + fixed_f) * 4 <= ws_size) break;
    NB >>= 1;
  }

  float* ws = (float*)d_ws;
  size_t off = 0;
  float* qkvraw = ws + off; off += (size_t)NB * D3_ * HWs;
  float* uni    = ws + off; off += (size_t)NB * 512 * HWs;
  float* S_part = ws + off; off += (size_t)32 * 32 * 4096;
  float* S      = ws + off; off += (size_t)32 * 4096;
  float* ssqp   = ws + off; off += (size_t)8 * 512 * 4;
  float* gpart  = ws + off; off += 1024;
  float* attnb  = ws + off; off += (size_t)32 * 4096;
  ushort_t* WH  = (ushort_t*)(ws + off);
  ushort_t* WL  = WH + (size_t)896 * 256;

  k0_wsplit<<<dim3(896), 256, 0, stream>>>(wqkv, gw1, WH, WL);

  for (int g = 0; g < B_ / NB; ++g) {
    const int bbase = g * NB;
    k1_mfma<<<dim3(128, 7, NB), 256, 0, stream>>>(WH, WL, x, gb1, gw2, gb2,
                                                  qkvraw, gpart, bbase);
    k3a_dw<<<dim3(4, 768, NB), 256, 0, stream>>>(qkvraw, wdw, uni, out, ssqp, bbase);
    k3b_gram<<<dim3(32, 4, NB), 256, 0, stream>>>(uni, S_part, bbase);
  }
  k3c_reduce<<<dim3(16, 32), 256, 0, stream>>>(S_part, S);
  k4_final<<<dim3(32), 256, 0, stream>>>(S, ssqp, gpart, temp,
                                         a1, a2, a3, a4, attnb);
  k5_av<<<dim3(128, 4, 8), 256, 0, stream>>>(attnb, out);
}